// Round 1
// baseline (664.842 us; speedup 1.0000x reference)
//
#include <hip/hip_runtime.h>
#include <hip/hip_bf16.h>
#include <math.h>

// Problem constants
#define B_ 8
#define T_ 64
#define N_ 512
#define F_ 32
#define G_ 64
#define C_ 64

// ---------------------------------------------------------------------------
// P0: d[b*N+i] = rsqrt(sum_j adj[b,i,j] + 1)   (deg>0 guard kept for fidelity)
// ---------------------------------------------------------------------------
__global__ __launch_bounds__(256) void deg_kernel(const float* __restrict__ adj,
                                                  float* __restrict__ d) {
  int row = blockIdx.x * 4 + (threadIdx.x >> 6);   // [0, B_*N_)
  int lane = threadIdx.x & 63;
  const float* r = adj + (size_t)row * N_;
  float s = 0.f;
  #pragma unroll
  for (int j = lane; j < N_; j += 64) s += r[j];
  #pragma unroll
  for (int m = 1; m < 64; m <<= 1) s += __shfl_xor(s, m);
  if (lane == 0) {
    float deg = s + 1.0f;
    d[row] = (deg > 0.f) ? rsqrtf(deg) : 0.f;
  }
}

// ---------------------------------------------------------------------------
// P1: weight-norm conv weights into [g][k][c] layout; W12 = W1+W2; b12 = b1+b2
// ---------------------------------------------------------------------------
__global__ __launch_bounds__(256) void prep_kernel(
    const float* __restrict__ v1, const float* __restrict__ g1,
    const float* __restrict__ v2, const float* __restrict__ g2,
    const float* __restrict__ W1, const float* __restrict__ W2,
    const float* __restrict__ b1, const float* __restrict__ b2,
    float* __restrict__ wn1, float* __restrict__ wn2,
    float* __restrict__ W12, float* __restrict__ b12) {
  int tid = threadIdx.x;
  if (tid < 64) {
    int c = tid;
    float s = 0.f;
    #pragma unroll 8
    for (int k = 0; k < G_ * 2; ++k) { float v = v1[c * (G_ * 2) + k]; s += v * v; }
    float sc = g1[c] / sqrtf(s);
    for (int g = 0; g < G_; ++g) {
      wn1[(g * 2 + 0) * C_ + c] = v1[c * (G_ * 2) + g * 2 + 0] * sc;
      wn1[(g * 2 + 1) * C_ + c] = v1[c * (G_ * 2) + g * 2 + 1] * sc;
    }
  } else if (tid < 128) {
    int c = tid - 64;
    float s = 0.f;
    #pragma unroll 8
    for (int k = 0; k < C_ * 2; ++k) { float v = v2[c * (C_ * 2) + k]; s += v * v; }
    float sc = g2[c] / sqrtf(s);
    for (int g = 0; g < C_; ++g) {
      wn2[(g * 2 + 0) * C_ + c] = v2[c * (C_ * 2) + g * 2 + 0] * sc;
      wn2[(g * 2 + 1) * C_ + c] = v2[c * (C_ * 2) + g * 2 + 1] * sc;
    }
  }
  for (int i = tid; i < C_ * C_; i += 256) W12[i] = W1[i] + W2[i];
  if (tid < 64) b12[tid] = b1[tid] + b2[tid];
}

// ---------------------------------------------------------------------------
// K1: h[b,t,i,f] = d_i * sum_j (adj[b,i,j]+delta_ij)*d_j * x[b,t,j,f]
// One 64-thread wg per (b, t, i-tile of 64). Register block 8i x 4f.
// LDS: a_t[j][i] (transposed, pad 68 -> 16B-aligned rows, 2-way-free b128
// reads), xs[j][f] linear.
// ---------------------------------------------------------------------------
__global__ __launch_bounds__(64) void gcn_kernel(
    const float* __restrict__ x, const float* __restrict__ adj,
    const float* __restrict__ d, float* __restrict__ h) {
  __shared__ float a_t[32][68];
  __shared__ float xs[32 * 32];

  int wg = blockIdx.x;            // ((b*64+t)*8 + it)
  int it = wg & 7;
  int bt = wg >> 3;
  int t = bt & 63;
  int b = bt >> 6;
  int i0 = it * 64;

  int l = threadIdx.x;
  int fb = l & 7;                  // f block (4 floats)
  int ib = l >> 3;                 // i block (8 rows)
  int jlane = l & 31;
  int hrow = l >> 5;

  float acc[32];
  #pragma unroll
  for (int k = 0; k < 32; ++k) acc[k] = 0.f;

  const size_t adj_b = (size_t)b * N_ * N_;
  const float* xbase = x + ((size_t)(b * T_ + t) * N_) * F_;

  for (int jt = 0; jt < N_; jt += 32) {
    // stage a (scaled by d_j, diag added)
    float dj = d[b * N_ + jt + jlane];
    #pragma unroll
    for (int s = 0; s < 32; ++s) {
      int r = 2 * s + hrow;
      int gi = i0 + r, gj = jt + jlane;
      float v = adj[adj_b + (size_t)gi * N_ + gj] + ((gi == gj) ? 1.f : 0.f);
      a_t[jlane][r] = v * dj;
    }
    // stage x: 32 rows x 32 f = 1024 floats, fully coalesced
    {
      const float4* src = (const float4*)(xbase + jt * F_ + l * 16);
      float4* dst = (float4*)&xs[l * 16];
      #pragma unroll
      for (int k = 0; k < 4; ++k) dst[k] = src[k];
    }
    __syncthreads();
    #pragma unroll 8
    for (int jj = 0; jj < 32; ++jj) {
      float4 xv = *(const float4*)&xs[jj * 32 + fb * 4];
      float4 a0 = *(const float4*)&a_t[jj][ib * 8];
      float4 a1 = *(const float4*)&a_t[jj][ib * 8 + 4];
      float ar[8] = {a0.x, a0.y, a0.z, a0.w, a1.x, a1.y, a1.z, a1.w};
      float xr[4] = {xv.x, xv.y, xv.z, xv.w};
      #pragma unroll
      for (int r = 0; r < 8; ++r)
        #pragma unroll
        for (int qq = 0; qq < 4; ++qq) acc[r * 4 + qq] += ar[r] * xr[qq];
    }
    __syncthreads();
  }
  // epilogue: scale by d_i, store h
  #pragma unroll
  for (int r = 0; r < 8; ++r) {
    int gi = i0 + ib * 8 + r;
    float di = d[b * N_ + gi];
    float4 o;
    o.x = acc[r * 4 + 0] * di;
    o.y = acc[r * 4 + 1] * di;
    o.z = acc[r * 4 + 2] * di;
    o.w = acc[r * 4 + 3] * di;
    *(float4*)(h + ((size_t)(b * T_ + t) * N_ + gi) * F_ + fb * 4) = o;
  }
}

// ---------------------------------------------------------------------------
// K2: per (b,n): seq = h@gcn_w + b; conv1; conv2 + skip; temporal attention;
// LayerNorm. 256 threads. LDS tiles padded to 65 (odd) -> conflict-free.
// Weights read with wave-uniform addresses -> scalar loads.
// ---------------------------------------------------------------------------
__global__ __launch_bounds__(256) void tcn_attn_kernel(
    const float* __restrict__ h, const float* __restrict__ gcn_w,
    const float* __restrict__ gcn_b, const float* __restrict__ wn1,
    const float* __restrict__ b1c, const float* __restrict__ wn2,
    const float* __restrict__ b2c, const float* __restrict__ W12,
    const float* __restrict__ b12, const float* __restrict__ Vw,
    const float* __restrict__ Vb, const float* __restrict__ ln_g,
    const float* __restrict__ ln_b, float* __restrict__ out) {
  __shared__ float seq[64][65];
  __shared__ float o1[64][65];
  __shared__ float tcnb[64][65];   // first 64*33 floats double as hh staging
  __shared__ float sp4[4][64];
  __shared__ float aw[64];

  int bn = blockIdx.x;
  int n = bn & (N_ - 1);
  int b = bn >> 9;
  int tid = threadIdx.x;
  int t = tid & 63;
  int q = __builtin_amdgcn_readfirstlane(tid >> 6);   // wave id, uniform

  float* hh = &tcnb[0][0];   // [64][33]

  // ---- stage h[b, :, n, :] -> hh (coalesced-ish float4 reads) ----
  {
    int tt = tid >> 2, p = tid & 3;
    const float* src = h + ((size_t)(b * T_ + tt) * N_ + n) * F_ + p * 8;
    float4 v0 = ((const float4*)src)[0];
    float4 v1v = ((const float4*)src)[1];
    float* dst = hh + tt * 33 + p * 8;
    dst[0] = v0.x; dst[1] = v0.y; dst[2] = v0.z; dst[3] = v0.w;
    dst[4] = v1v.x; dst[5] = v1v.y; dst[6] = v1v.z; dst[7] = v1v.w;
  }
  __syncthreads();

  // ---- seq[g][t] = sum_f hh[t][f]*gcn_w[f][g] + gcn_b[g] ----
  {
    int g0 = q << 4;
    float acc[16];
    #pragma unroll
    for (int i = 0; i < 16; ++i) acc[i] = gcn_b[g0 + i];
    #pragma unroll 4
    for (int f = 0; f < F_; ++f) {
      float hv = hh[t * 33 + f];
      #pragma unroll
      for (int i = 0; i < 16; ++i) acc[i] += hv * gcn_w[f * G_ + g0 + i];
    }
    #pragma unroll
    for (int i = 0; i < 16; ++i) seq[g0 + i][t] = acc[i];
  }
  __syncthreads();

  // ---- conv1: o1 = relu(wn1 * seq + b1c), causal dilation 2 ----
  {
    int c0 = q << 4;
    float acc[16];
    #pragma unroll
    for (int i = 0; i < 16; ++i) acc[i] = b1c[c0 + i];
    #pragma unroll 4
    for (int g = 0; g < G_; ++g) {
      float sp = (t >= 2) ? seq[g][t - 2] : 0.f;
      float sc = seq[g][t];
      const float* w0 = &wn1[(g * 2 + 0) * C_ + c0];
      const float* w1w = &wn1[(g * 2 + 1) * C_ + c0];
      #pragma unroll
      for (int i = 0; i < 16; ++i) acc[i] += w0[i] * sp + w1w[i] * sc;
    }
    #pragma unroll
    for (int i = 0; i < 16; ++i) o1[c0 + i][t] = fmaxf(acc[i], 0.f);
  }
  __syncthreads();

  // ---- conv2 + skip: tcn = relu(relu(wn2*o1 + b2c) + seq) ----
  {
    int c0 = q << 4;
    float acc[16];
    #pragma unroll
    for (int i = 0; i < 16; ++i) acc[i] = b2c[c0 + i];
    #pragma unroll 4
    for (int g = 0; g < C_; ++g) {
      float sp = (t >= 2) ? o1[g][t - 2] : 0.f;
      float sc = o1[g][t];
      const float* w0 = &wn2[(g * 2 + 0) * C_ + c0];
      const float* w1w = &wn2[(g * 2 + 1) * C_ + c0];
      #pragma unroll
      for (int i = 0; i < 16; ++i) acc[i] += w0[i] * sp + w1w[i] * sc;
    }
    #pragma unroll
    for (int i = 0; i < 16; ++i) {
      float o2 = fmaxf(acc[i], 0.f);
      tcnb[c0 + i][t] = fmaxf(o2 + seq[c0 + i][t], 0.f);
    }
  }
  __syncthreads();

  // ---- attention scores: s[t] = sum_d Vw[d]*tanh(sum_c tcn[c][t]*W12[d][c]+b12[d]) ----
  {
    float tc[64];
    #pragma unroll
    for (int c = 0; c < 64; ++c) tc[c] = tcnb[c][t];
    float part = 0.f;
    for (int dd = 0; dd < 16; ++dd) {
      int dI = (q << 4) + dd;
      float s = b12[dI];
      #pragma unroll
      for (int c = 0; c < 64; ++c) s += tc[c] * W12[dI * C_ + c];
      part += Vw[dI] * tanhf(s);
    }
    sp4[q][t] = part;
  }
  __syncthreads();

  // ---- softmax over t (wave 0) ----
  if (tid < 64) {
    float s = sp4[0][t] + sp4[1][t] + sp4[2][t] + sp4[3][t] + Vb[0];
    float m = s;
    #pragma unroll
    for (int msk = 1; msk < 64; msk <<= 1) m = fmaxf(m, __shfl_xor(m, msk));
    float e = __expf(s - m);
    float su = e;
    #pragma unroll
    for (int msk = 1; msk < 64; msk <<= 1) su += __shfl_xor(su, msk);
    aw[t] = e / su;
  }
  __syncthreads();

  // ---- attn[c] = sum_t tcn[c][t]*aw[t] (partial per wave) ----
  {
    int c = t;
    float pa = 0.f;
    #pragma unroll
    for (int k = 0; k < 16; ++k) {
      int tt = (q << 4) + k;
      pa += tcnb[c][tt] * aw[tt];
    }
    sp4[q][c] = pa;
  }
  __syncthreads();

  // ---- LayerNorm over c + store ----
  if (tid < 64) {
    int c = tid;
    float a = sp4[0][c] + sp4[1][c] + sp4[2][c] + sp4[3][c];
    float su = a;
    #pragma unroll
    for (int msk = 1; msk < 64; msk <<= 1) su += __shfl_xor(su, msk);
    float mu = su * (1.f / 64.f);
    float dv = a - mu;
    float vv = dv * dv;
    #pragma unroll
    for (int msk = 1; msk < 64; msk <<= 1) vv += __shfl_xor(vv, msk);
    float var = vv * (1.f / 64.f);
    float rs = rsqrtf(var + 1e-5f);
    out[(size_t)bn * C_ + c] = dv * rs * ln_g[c] + ln_b[c];
  }
}

// ---------------------------------------------------------------------------
extern "C" void kernel_launch(void* const* d_in, const int* in_sizes, int n_in,
                              void* d_out, int out_size, void* d_ws, size_t ws_size,
                              hipStream_t stream) {
  (void)in_sizes; (void)n_in; (void)out_size; (void)ws_size;
  const float* x     = (const float*)d_in[0];
  const float* adj   = (const float*)d_in[1];
  const float* gcn_w = (const float*)d_in[2];
  const float* gcn_b = (const float*)d_in[3];
  const float* v1    = (const float*)d_in[4];
  const float* g1    = (const float*)d_in[5];
  const float* b1c   = (const float*)d_in[6];
  const float* v2    = (const float*)d_in[7];
  const float* g2    = (const float*)d_in[8];
  const float* b2c   = (const float*)d_in[9];
  const float* W1    = (const float*)d_in[10];
  const float* b1    = (const float*)d_in[11];
  const float* W2    = (const float*)d_in[12];
  const float* b2    = (const float*)d_in[13];
  const float* Vw    = (const float*)d_in[14];
  const float* Vb    = (const float*)d_in[15];
  const float* ln_g  = (const float*)d_in[16];
  const float* ln_b  = (const float*)d_in[17];
  float* out = (float*)d_out;

  char* ws = (char*)d_ws;
  float* h   = (float*)(ws);                    // 8*64*512*32 f32 = 33554432 B
  float* dd  = (float*)(ws + 33554432);         // 4096 f32
  float* wn1 = (float*)(ws + 33570816);         // 8192 f32
  float* wn2 = (float*)(ws + 33603584);         // 8192 f32
  float* W12 = (float*)(ws + 33636352);         // 4096 f32
  float* b12 = (float*)(ws + 33652736);         // 64 f32

  deg_kernel<<<(B_ * N_) / 4, 256, 0, stream>>>(adj, dd);
  prep_kernel<<<1, 256, 0, stream>>>(v1, g1, v2, g2, W1, W2, b1, b2,
                                     wn1, wn2, W12, b12);
  gcn_kernel<<<B_ * T_ * (N_ / 64), 64, 0, stream>>>(x, adj, dd, h);
  tcn_attn_kernel<<<B_ * N_, 256, 0, stream>>>(h, gcn_w, gcn_b, wn1, b1c,
                                               wn2, b2c, W12, b12, Vw, Vb,
                                               ln_g, ln_b, out);
}

// Round 2
// 573.936 us; speedup vs baseline: 1.1584x; 1.1584x over previous
//
#include <hip/hip_runtime.h>
#include <hip/hip_bf16.h>
#include <math.h>

#define B_ 8
#define T_ 64
#define N_ 512
#define F_ 32
#define G_ 64
#define C_ 64

typedef __attribute__((ext_vector_type(8))) short short8;
typedef __attribute__((ext_vector_type(4))) float f32x4;
typedef __attribute__((ext_vector_type(2))) float f32x2;

__device__ __forceinline__ unsigned short f2bf(float x) {
  unsigned u = __float_as_uint(x);
  u += 0x7fffu + ((u >> 16) & 1u);
  return (unsigned short)(u >> 16);
}
__device__ __forceinline__ float bf2f(unsigned short h) {
  return __uint_as_float(((unsigned)h) << 16);
}

// ---------------------------------------------------------------------------
// P0: d[b*N+i] = rsqrt(deg)
// ---------------------------------------------------------------------------
__global__ __launch_bounds__(256) void deg_kernel(const float* __restrict__ adj,
                                                  float* __restrict__ d) {
  int row = blockIdx.x * 4 + (threadIdx.x >> 6);
  int lane = threadIdx.x & 63;
  const float* r = adj + (size_t)row * N_;
  float s = 0.f;
  #pragma unroll
  for (int j = lane; j < N_; j += 64) s += r[j];
  #pragma unroll
  for (int m = 1; m < 64; m <<= 1) s += __shfl_xor(s, m);
  if (lane == 0) {
    float deg = s + 1.0f;
    d[row] = (deg > 0.f) ? rsqrtf(deg) : 0.f;
  }
}

// ---------------------------------------------------------------------------
// P0b: Abf[b][i][j] = bf16((adj+I) * d_i * d_j)
// ---------------------------------------------------------------------------
__global__ __launch_bounds__(256) void abf_kernel(const float* __restrict__ adj,
                                                  const float* __restrict__ d,
                                                  unsigned short* __restrict__ Abf) {
  int row = blockIdx.x * 4 + (threadIdx.x >> 6);
  int lane = threadIdx.x & 63;
  int b = row >> 9;
  int i = row & (N_ - 1);
  float di = d[row];
  const float* src = adj + (size_t)row * N_;
  unsigned short* dst = Abf + (size_t)row * N_;
  int j0 = lane * 8;
  float4 v0 = *(const float4*)(src + j0);
  float4 v1 = *(const float4*)(src + j0 + 4);
  float vals[8] = {v0.x, v0.y, v0.z, v0.w, v1.x, v1.y, v1.z, v1.w};
  unsigned short o[8];
  #pragma unroll
  for (int k = 0; k < 8; ++k) {
    int j = j0 + k;
    float a = vals[k] + ((i == j) ? 1.f : 0.f);
    o[k] = f2bf(a * di * d[b * N_ + j]);
  }
  uint4 pv;
  pv.x = (unsigned)o[0] | ((unsigned)o[1] << 16);
  pv.y = (unsigned)o[2] | ((unsigned)o[3] << 16);
  pv.z = (unsigned)o[4] | ((unsigned)o[5] << 16);
  pv.w = (unsigned)o[6] | ((unsigned)o[7] << 16);
  *(uint4*)(dst + j0) = pv;
}

// ---------------------------------------------------------------------------
// P0c: xT[b][t][f][j] = bf16(x[b][t][j][f])   (K-major for MFMA B operand)
// ---------------------------------------------------------------------------
__global__ __launch_bounds__(256) void xT_kernel(const float* __restrict__ x,
                                                 unsigned short* __restrict__ xT) {
  __shared__ float tile[64][33];
  int bt = blockIdx.x;  // b*T + t
  int tid = threadIdx.x;
  const float* src = x + (size_t)bt * N_ * F_;
  unsigned short* dst = xT + (size_t)bt * F_ * N_;
  for (int j0 = 0; j0 < N_; j0 += 64) {
    #pragma unroll
    for (int kk = 0; kk < 2; ++kk) {
      int qq = tid + 256 * kk;       // float4 id 0..511
      int jl = qq >> 3, fc = qq & 7;
      float4 v = *(const float4*)(src + (size_t)(j0 + jl) * F_ + fc * 4);
      tile[jl][fc * 4 + 0] = v.x;
      tile[jl][fc * 4 + 1] = v.y;
      tile[jl][fc * 4 + 2] = v.z;
      tile[jl][fc * 4 + 3] = v.w;
    }
    __syncthreads();
    {
      int u = tid & 31, fr = tid >> 5;
      #pragma unroll
      for (int ff = 0; ff < 4; ++ff) {
        int f = fr + ff * 8;
        unsigned lo = f2bf(tile[2 * u][f]);
        unsigned hi = f2bf(tile[2 * u + 1][f]);
        ((unsigned*)(dst + (size_t)f * N_ + j0))[u] = lo | (hi << 16);
      }
    }
    __syncthreads();
  }
}

// ---------------------------------------------------------------------------
// P1: weight-norm -> wn[(g*2+k)*C + c]; W12 = W1+W2; b12 = b1+b2
// grid 144: blk 0..63 -> wn1 ch, 64..127 -> wn2 ch, 128..143 -> W12/b12
// ---------------------------------------------------------------------------
__global__ __launch_bounds__(256) void prep_kernel(
    const float* __restrict__ v1, const float* __restrict__ g1,
    const float* __restrict__ v2, const float* __restrict__ g2,
    const float* __restrict__ W1, const float* __restrict__ W2,
    const float* __restrict__ b1, const float* __restrict__ b2,
    float* __restrict__ wn1, float* __restrict__ wn2,
    float* __restrict__ W12, float* __restrict__ b12) {
  int blk = blockIdx.x;
  int tid = threadIdx.x;
  if (blk < 128) {
    __shared__ float red[4];
    int c = blk & 63;
    const float* v = (blk < 64) ? v1 : v2;
    const float* g = (blk < 64) ? g1 : g2;
    float* wn = (blk < 64) ? wn1 : wn2;
    float s = 0.f;
    if (tid < 128) { float t = v[c * 128 + tid]; s = t * t; }
    #pragma unroll
    for (int m = 1; m < 64; m <<= 1) s += __shfl_xor(s, m);
    if ((tid & 63) == 0) red[tid >> 6] = s;
    __syncthreads();
    float sc = g[c] / sqrtf(red[0] + red[1] + red[2] + red[3]);
    if (tid < 128) wn[tid * 64 + c] = v[c * 128 + tid] * sc;
  } else {
    int idx = (blk - 128) * 256 + tid;
    W12[idx] = W1[idx] + W2[idx];
    if (blk == 128 && tid < 64) b12[tid] = b1[tid] + b2[tid];
  }
}

// ---------------------------------------------------------------------------
// K1: MFMA GCN.  h[b,t,i,f] (bf16) = [Abf(b) @ X(b)] ; per-wg 64i x 64col
// (col = tt*32+f, 2 t's), 4 waves in 2x2, each 2x2 16x16x32 frags, K=512.
// ---------------------------------------------------------------------------
__global__ __launch_bounds__(256) void gcn_mfma_kernel(
    const unsigned short* __restrict__ Abf, const unsigned short* __restrict__ xT,
    unsigned short* __restrict__ h) {
  __shared__ unsigned short as_[64][40];   // [i][j] pad 40 -> 16B-aligned, ~free
  __shared__ unsigned short xs_[64][40];   // [col][j]

  int blk = blockIdx.x;
  int b = blk >> 8;
  int rem = blk & 255;
  int i0 = (rem >> 5) * 64;
  int t0 = (rem & 31) * 2;

  int tid = threadIdx.x;
  int l = tid & 63;
  int wq = tid >> 6;
  int wr = wq >> 1, wc = wq & 1;
  int lr = l & 15;
  int lk = (l >> 4) * 8;

  f32x4 acc00 = {0.f, 0.f, 0.f, 0.f}, acc01 = acc00, acc10 = acc00, acc11 = acc00;

  int srow = tid >> 2;            // 0..63
  int schunk = (tid & 3) * 8;     // bf16 elem offset within 32-wide K tile

  const unsigned short* aSrc =
      Abf + ((size_t)(b * N_ + i0 + srow)) * N_ + schunk;
  int ttS = srow >> 5, fS = srow & 31;
  const unsigned short* xSrc =
      xT + ((size_t)((b * T_ + t0 + ttS) * F_ + fS)) * N_ + schunk;

  for (int j0 = 0; j0 < N_; j0 += 32) {
    *(short8*)&as_[srow][schunk] = *(const short8*)(aSrc + j0);
    *(short8*)&xs_[srow][schunk] = *(const short8*)(xSrc + j0);
    __syncthreads();
    short8 a0 = *(const short8*)&as_[wr * 32 + lr][lk];
    short8 a1 = *(const short8*)&as_[wr * 32 + 16 + lr][lk];
    short8 bb0 = *(const short8*)&xs_[wc * 32 + lr][lk];
    short8 bb1 = *(const short8*)&xs_[wc * 32 + 16 + lr][lk];
    acc00 = __builtin_amdgcn_mfma_f32_16x16x32_bf16(a0, bb0, acc00, 0, 0, 0);
    acc01 = __builtin_amdgcn_mfma_f32_16x16x32_bf16(a0, bb1, acc01, 0, 0, 0);
    acc10 = __builtin_amdgcn_mfma_f32_16x16x32_bf16(a1, bb0, acc10, 0, 0, 0);
    acc11 = __builtin_amdgcn_mfma_f32_16x16x32_bf16(a1, bb1, acc11, 0, 0, 0);
    __syncthreads();
  }

  int ibase = i0 + wr * 32 + (l >> 4) * 4;
  int cbase = wc * 32 + (l & 15);
  f32x4 accs[2][2] = {{acc00, acc01}, {acc10, acc11}};
  #pragma unroll
  for (int si = 0; si < 2; ++si)
    #pragma unroll
    for (int sc = 0; sc < 2; ++sc) {
      int col = cbase + sc * 16;
      int t = t0 + (col >> 5), f = col & 31;
      #pragma unroll
      for (int v = 0; v < 4; ++v) {
        int i = ibase + si * 16 + v;
        h[((size_t)((b * T_ + t) * N_ + i)) * F_ + f] = f2bf(accs[si][sc][v]);
      }
    }
}

// ---------------------------------------------------------------------------
// K2: per (b,n): seq GEMM, conv1, conv2+skip, attention, LayerNorm.
// lane = output channel, wave q handles t-block [q*16, q*16+16).
// Weights: per-lane coalesced VGPR loads. Activations: broadcast LDS rows.
// Stride 66: per-lane-row writes 2-way (free) and 8B-aligned f32x2 reads.
// ---------------------------------------------------------------------------
__global__ __launch_bounds__(256) void tcn_attn_kernel(
    const unsigned short* __restrict__ h, const float* __restrict__ gcn_w,
    const float* __restrict__ gcn_b, const float* __restrict__ wn1,
    const float* __restrict__ b1c, const float* __restrict__ wn2,
    const float* __restrict__ b2c, const float* __restrict__ W12,
    const float* __restrict__ b12, const float* __restrict__ Vw,
    const float* __restrict__ Vb, const float* __restrict__ ln_g,
    const float* __restrict__ ln_b, float* __restrict__ out) {
  __shared__ float seqS[64 * 66];
  __shared__ float o1S[64 * 66];    // first 32*66 floats double as hhT[f][t]
  __shared__ float tcnS[64 * 66];
  __shared__ float sp4[4][64];
  __shared__ float awS[64];

  int bn = blockIdx.x;
  int n = bn & (N_ - 1);
  int b = bn >> 9;
  int tid = threadIdx.x;
  int lane = tid & 63;
  int q = tid >> 6;
  int tb = q * 16;

  float* hhT = o1S;   // [32][66]

  // ---- phase 0: stage h[b,:,n,:] -> hhT[f][t] ----
  {
    int t = tid >> 2, p = tid & 3;
    const unsigned short* src = h + ((size_t)((b * T_ + t) * N_ + n)) * F_ + p * 8;
    short8 v = *(const short8*)src;
    #pragma unroll
    for (int ff = 0; ff < 8; ++ff)
      hhT[(p * 8 + ff) * 66 + t] = bf2f((unsigned short)v[ff]);
  }
  __syncthreads();

  // ---- phase 1: seq[g][t] = sum_f hhT[f][t]*gcn_w[f][g] + gcn_b[g] ----
  {
    float acc[16];
    float bb = gcn_b[lane];
    #pragma unroll
    for (int t = 0; t < 16; ++t) acc[t] = bb;
    #pragma unroll 4
    for (int f = 0; f < F_; ++f) {
      float wf = gcn_w[f * G_ + lane];
      const float* row = &hhT[f * 66 + tb];
      #pragma unroll
      for (int p = 0; p < 8; ++p) {
        f32x2 v = *(const f32x2*)&row[2 * p];
        acc[2 * p]     += wf * v.x;
        acc[2 * p + 1] += wf * v.y;
      }
    }
    #pragma unroll
    for (int t = 0; t < 16; ++t) seqS[lane * 66 + tb + t] = acc[t];
  }
  __syncthreads();

  // ---- phase 2: conv1  o1 = relu(wn1 * seq + b1c), causal dil 2 ----
  {
    float a2[16];
    float bb = b1c[lane];
    #pragma unroll
    for (int t = 0; t < 16; ++t) a2[t] = bb;
    for (int gb = 0; gb < 4; ++gb) {
      float w0[16], w1[16];
      #pragma unroll
      for (int gg = 0; gg < 16; ++gg) {
        int g = gb * 16 + gg;
        w0[gg] = wn1[(2 * g) * C_ + lane];
        w1[gg] = wn1[(2 * g + 1) * C_ + lane];
      }
      #pragma unroll
      for (int gg = 0; gg < 16; ++gg) {
        int g = gb * 16 + gg;
        const float* row = &seqS[g * 66];
        float cur[16];
        #pragma unroll
        for (int p = 0; p < 8; ++p) {
          f32x2 v = *(const f32x2*)&row[tb + 2 * p];
          cur[2 * p] = v.x; cur[2 * p + 1] = v.y;
        }
        float pm2 = 0.f, pm1 = 0.f;
        if (tb > 0) { f32x2 v = *(const f32x2*)&row[tb - 2]; pm2 = v.x; pm1 = v.y; }
        a2[0] += w0[gg] * pm2 + w1[gg] * cur[0];
        a2[1] += w0[gg] * pm1 + w1[gg] * cur[1];
        #pragma unroll
        for (int t = 2; t < 16; ++t) a2[t] += w0[gg] * cur[t - 2] + w1[gg] * cur[t];
      }
    }
    #pragma unroll
    for (int t = 0; t < 16; ++t) o1S[lane * 66 + tb + t] = fmaxf(a2[t], 0.f);
  }
  __syncthreads();

  // ---- phase 2b: conv2 + skip: tcn = relu(relu(wn2*o1 + b2c) + seq) ----
  {
    float a2[16];
    float bb = b2c[lane];
    #pragma unroll
    for (int t = 0; t < 16; ++t) a2[t] = bb;
    for (int gb = 0; gb < 4; ++gb) {
      float w0[16], w1[16];
      #pragma unroll
      for (int gg = 0; gg < 16; ++gg) {
        int g = gb * 16 + gg;
        w0[gg] = wn2[(2 * g) * C_ + lane];
        w1[gg] = wn2[(2 * g + 1) * C_ + lane];
      }
      #pragma unroll
      for (int gg = 0; gg < 16; ++gg) {
        int g = gb * 16 + gg;
        const float* row = &o1S[g * 66];
        float cur[16];
        #pragma unroll
        for (int p = 0; p < 8; ++p) {
          f32x2 v = *(const f32x2*)&row[tb + 2 * p];
          cur[2 * p] = v.x; cur[2 * p + 1] = v.y;
        }
        float pm2 = 0.f, pm1 = 0.f;
        if (tb > 0) { f32x2 v = *(const f32x2*)&row[tb - 2]; pm2 = v.x; pm1 = v.y; }
        a2[0] += w0[gg] * pm2 + w1[gg] * cur[0];
        a2[1] += w0[gg] * pm1 + w1[gg] * cur[1];
        #pragma unroll
        for (int t = 2; t < 16; ++t) a2[t] += w0[gg] * cur[t - 2] + w1[gg] * cur[t];
      }
    }
    #pragma unroll
    for (int t = 0; t < 16; ++t) {
      float sk = seqS[lane * 66 + tb + t];
      tcnS[lane * 66 + tb + t] = fmaxf(fmaxf(a2[t], 0.f) + sk, 0.f);
    }
  }
  __syncthreads();

  // ---- phase 3: scores. lane = t; wave q handles d in [q*16, q*16+16) ----
  {
    float tc[64];
    #pragma unroll
    for (int cc = 0; cc < 64; ++cc) tc[cc] = tcnS[cc * 66 + lane];
    float part = 0.f;
    for (int dd = 0; dd < 16; ++dd) {
      int dI = tb + dd;
      float s = b12[dI];
      #pragma unroll
      for (int cc = 0; cc < 64; ++cc) s += tc[cc] * W12[dI * C_ + cc];
      float e = __expf(2.f * s);              // tanh(s) = 1 - 2/(e^{2s}+1)
      part += Vw[dI] * (1.f - 2.f / (e + 1.f));
    }
    sp4[q][lane] = part;
  }
  __syncthreads();

  // ---- phase 4: softmax over t (wave 0) ----
  if (tid < 64) {
    float s = sp4[0][lane] + sp4[1][lane] + sp4[2][lane] + sp4[3][lane] + Vb[0];
    float m = s;
    #pragma unroll
    for (int msk = 1; msk < 64; msk <<= 1) m = fmaxf(m, __shfl_xor(m, msk));
    float e = __expf(s - m);
    float su = e;
    #pragma unroll
    for (int msk = 1; msk < 64; msk <<= 1) su += __shfl_xor(su, msk);
    awS[lane] = e / su;
  }
  __syncthreads();

  // ---- phase 5: attn[c] partial over this wave's t-block ----
  {
    float pa = 0.f;
    #pragma unroll
    for (int k = 0; k < 16; ++k) pa += tcnS[lane * 66 + tb + k] * awS[tb + k];
    sp4[q][lane] = pa;
  }
  __syncthreads();

  // ---- phase 6: LayerNorm over c ----
  if (tid < 64) {
    int c = lane;
    float a = sp4[0][c] + sp4[1][c] + sp4[2][c] + sp4[3][c];
    float su = a;
    #pragma unroll
    for (int msk = 1; msk < 64; msk <<= 1) su += __shfl_xor(su, msk);
    float mu = su * (1.f / 64.f);
    float dv = a - mu;
    float vv = dv * dv;
    #pragma unroll
    for (int msk = 1; msk < 64; msk <<= 1) vv += __shfl_xor(vv, msk);
    float rs = rsqrtf(vv * (1.f / 64.f) + 1e-5f);
    out[(size_t)bn * C_ + c] = dv * rs * ln_g[c] + ln_b[c];
  }
}

// ---------------------------------------------------------------------------
extern "C" void kernel_launch(void* const* d_in, const int* in_sizes, int n_in,
                              void* d_out, int out_size, void* d_ws, size_t ws_size,
                              hipStream_t stream) {
  (void)in_sizes; (void)n_in; (void)out_size; (void)ws_size;
  const float* x     = (const float*)d_in[0];
  const float* adj   = (const float*)d_in[1];
  const float* gcn_w = (const float*)d_in[2];
  const float* gcn_b = (const float*)d_in[3];
  const float* v1    = (const float*)d_in[4];
  const float* g1    = (const float*)d_in[5];
  const float* b1c   = (const float*)d_in[6];
  const float* v2    = (const float*)d_in[7];
  const float* g2    = (const float*)d_in[8];
  const float* b2c   = (const float*)d_in[9];
  const float* W1    = (const float*)d_in[10];
  const float* b1    = (const float*)d_in[11];
  const float* W2    = (const float*)d_in[12];
  const float* b2    = (const float*)d_in[13];
  const float* Vw    = (const float*)d_in[14];
  const float* Vb    = (const float*)d_in[15];
  const float* ln_g  = (const float*)d_in[16];
  const float* ln_b  = (const float*)d_in[17];
  float* out = (float*)d_out;

  char* ws = (char*)d_ws;
  unsigned short* h   = (unsigned short*)(ws);              // 16,777,216 B
  unsigned short* Abf = (unsigned short*)(ws + 16777216);   //  4,194,304 B
  unsigned short* xT  = (unsigned short*)(ws + 20971520);   // 16,777,216 B
  float* dd  = (float*)(ws + 37748736);                     //     16,384 B
  float* wn1 = (float*)(ws + 37765120);                     //     32,768 B
  float* wn2 = (float*)(ws + 37797888);                     //     32,768 B
  float* W12 = (float*)(ws + 37830656);                     //     16,384 B
  float* b12 = (float*)(ws + 37847040);                     //        256 B

  deg_kernel<<<(B_ * N_) / 4, 256, 0, stream>>>(adj, dd);
  abf_kernel<<<(B_ * N_) / 4, 256, 0, stream>>>(adj, dd, Abf);
  xT_kernel<<<B_ * T_, 256, 0, stream>>>(x, xT);
  prep_kernel<<<144, 256, 0, stream>>>(v1, g1, v2, g2, W1, W2, b1, b2,
                                       wn1, wn2, W12, b12);
  gcn_mfma_kernel<<<B_ * 256, 256, 0, stream>>>(Abf, xT, h);
  tcn_attn_kernel<<<B_ * N_, 256, 0, stream>>>(h, gcn_w, gcn_b, wn1, b1c,
                                               wn2, b2c, W12, b12, Vw, Vb,
                                               ln_g, ln_b, out);
}

// Round 4
// 187.253 us; speedup vs baseline: 3.5505x; 3.0650x over previous
//
#include <hip/hip_runtime.h>
#include <hip/hip_bf16.h>
#include <math.h>

#define B_ 8
#define T_ 64
#define N_ 512
#define F_ 32
#define G_ 64
#define C_ 64

typedef __attribute__((ext_vector_type(8))) short short8;
typedef __attribute__((ext_vector_type(4))) float f32x4;
typedef __attribute__((ext_vector_type(2))) float f32x2;

__device__ __forceinline__ unsigned short f2bf(float x) {
  unsigned u = __float_as_uint(x);
  u += 0x7fffu + ((u >> 16) & 1u);
  return (unsigned short)(u >> 16);
}
__device__ __forceinline__ float bf2f(unsigned short h) {
  return __uint_as_float(((unsigned)h) << 16);
}
__device__ __forceinline__ uint2 pack4(float a, float b, float c, float d) {
  uint2 r;
  r.x = (unsigned)f2bf(a) | ((unsigned)f2bf(b) << 16);
  r.y = (unsigned)f2bf(c) | ((unsigned)f2bf(d) << 16);
  return r;
}

// ---------------------------------------------------------------------------
// P0: d[b*N+i] = rsqrt(deg)
// ---------------------------------------------------------------------------
__global__ __launch_bounds__(256) void deg_kernel(const float* __restrict__ adj,
                                                  float* __restrict__ d) {
  int row = blockIdx.x * 4 + (threadIdx.x >> 6);
  int lane = threadIdx.x & 63;
  const float* r = adj + (size_t)row * N_;
  float s = 0.f;
  #pragma unroll
  for (int j = lane; j < N_; j += 64) s += r[j];
  #pragma unroll
  for (int m = 1; m < 64; m <<= 1) s += __shfl_xor(s, m);
  if (lane == 0) {
    float deg = s + 1.0f;
    d[row] = (deg > 0.f) ? rsqrtf(deg) : 0.f;
  }
}

// ---------------------------------------------------------------------------
// P0b: Abf[b][i][j] = bf16((adj+I) * d_i * d_j)
// ---------------------------------------------------------------------------
__global__ __launch_bounds__(256) void abf_kernel(const float* __restrict__ adj,
                                                  const float* __restrict__ d,
                                                  unsigned short* __restrict__ Abf) {
  int row = blockIdx.x * 4 + (threadIdx.x >> 6);
  int lane = threadIdx.x & 63;
  int b = row >> 9;
  int i = row & (N_ - 1);
  float di = d[row];
  const float* src = adj + (size_t)row * N_;
  unsigned short* dst = Abf + (size_t)row * N_;
  int j0 = lane * 8;
  float4 v0 = *(const float4*)(src + j0);
  float4 v1 = *(const float4*)(src + j0 + 4);
  float vals[8] = {v0.x, v0.y, v0.z, v0.w, v1.x, v1.y, v1.z, v1.w};
  unsigned short o[8];
  #pragma unroll
  for (int k = 0; k < 8; ++k) {
    int j = j0 + k;
    float a = vals[k] + ((i == j) ? 1.f : 0.f);
    o[k] = f2bf(a * di * d[b * N_ + j]);
  }
  uint4 pv;
  pv.x = (unsigned)o[0] | ((unsigned)o[1] << 16);
  pv.y = (unsigned)o[2] | ((unsigned)o[3] << 16);
  pv.z = (unsigned)o[4] | ((unsigned)o[5] << 16);
  pv.w = (unsigned)o[6] | ((unsigned)o[7] << 16);
  *(uint4*)(dst + j0) = pv;
}

// ---------------------------------------------------------------------------
// P0c: xT[b][t][f][j] = bf16(x[b][t][j][f])
// ---------------------------------------------------------------------------
__global__ __launch_bounds__(256) void xT_kernel(const float* __restrict__ x,
                                                 unsigned short* __restrict__ xT) {
  __shared__ float tile[64][33];
  int bt = blockIdx.x;
  int tid = threadIdx.x;
  const float* src = x + (size_t)bt * N_ * F_;
  unsigned short* dst = xT + (size_t)bt * F_ * N_;
  for (int j0 = 0; j0 < N_; j0 += 64) {
    #pragma unroll
    for (int kk = 0; kk < 2; ++kk) {
      int qq = tid + 256 * kk;
      int jl = qq >> 3, fc = qq & 7;
      float4 v = *(const float4*)(src + (size_t)(j0 + jl) * F_ + fc * 4);
      tile[jl][fc * 4 + 0] = v.x;
      tile[jl][fc * 4 + 1] = v.y;
      tile[jl][fc * 4 + 2] = v.z;
      tile[jl][fc * 4 + 3] = v.w;
    }
    __syncthreads();
    {
      int u = tid & 31, fr = tid >> 5;
      #pragma unroll
      for (int ff = 0; ff < 4; ++ff) {
        int f = fr + ff * 8;
        unsigned lo = f2bf(tile[2 * u][f]);
        unsigned hi = f2bf(tile[2 * u + 1][f]);
        ((unsigned*)(dst + (size_t)f * N_ + j0))[u] = lo | (hi << 16);
      }
    }
    __syncthreads();
  }
}

// ---------------------------------------------------------------------------
// P1: prep weights.
// blk 0..63:  wn1 -> w1a/w1b bf16 [c][g]
// blk 64..127: wn2 -> w2a/w2b
// blk 128: W12bf[d][c] = bf16(W1+W2), b12 = b1+b2
// blk 129: gw_bf[g][f] = bf16(gcn_w[f][g])
// ---------------------------------------------------------------------------
__global__ __launch_bounds__(256) void prep_kernel(
    const float* __restrict__ v1, const float* __restrict__ g1,
    const float* __restrict__ v2, const float* __restrict__ g2,
    const float* __restrict__ W1, const float* __restrict__ W2,
    const float* __restrict__ b1, const float* __restrict__ b2,
    const float* __restrict__ gcn_w,
    unsigned short* __restrict__ w1a, unsigned short* __restrict__ w1b,
    unsigned short* __restrict__ w2a, unsigned short* __restrict__ w2b,
    unsigned short* __restrict__ W12bf, float* __restrict__ b12,
    unsigned short* __restrict__ gw_bf) {
  int blk = blockIdx.x;
  int tid = threadIdx.x;
  if (blk < 128) {
    __shared__ float red[4];
    int c = blk & 63;
    const float* v = (blk < 64) ? v1 : v2;
    const float* g = (blk < 64) ? g1 : g2;
    unsigned short* wa = (blk < 64) ? w1a : w2a;
    unsigned short* wb = (blk < 64) ? w1b : w2b;
    float s = 0.f;
    if (tid < 128) { float t = v[c * 128 + tid]; s = t * t; }
    #pragma unroll
    for (int m = 1; m < 64; m <<= 1) s += __shfl_xor(s, m);
    if ((tid & 63) == 0) red[tid >> 6] = s;
    __syncthreads();
    float sc = g[c] / sqrtf(red[0] + red[1] + red[2] + red[3]);
    if (tid < 64) {
      int gg = tid;
      wa[c * 64 + gg] = f2bf(v[c * 128 + 2 * gg] * sc);
      wb[c * 64 + gg] = f2bf(v[c * 128 + 2 * gg + 1] * sc);
    }
  } else if (blk == 128) {
    for (int i = tid; i < 4096; i += 256) W12bf[i] = f2bf(W1[i] + W2[i]);
    if (tid < 64) b12[tid] = b1[tid] + b2[tid];
  } else {
    for (int i = tid; i < 2048; i += 256) {
      int g = i >> 5, f = i & 31;
      gw_bf[g * 32 + f] = f2bf(gcn_w[f * 64 + g]);
    }
  }
}

// ---------------------------------------------------------------------------
// K1: MFMA GCN (unchanged from R2). h[b,t,i,f] bf16.
// ---------------------------------------------------------------------------
__global__ __launch_bounds__(256) void gcn_mfma_kernel(
    const unsigned short* __restrict__ Abf, const unsigned short* __restrict__ xT,
    unsigned short* __restrict__ h) {
  __shared__ unsigned short as_[64][40];
  __shared__ unsigned short xs_[64][40];

  int blk = blockIdx.x;
  int b = blk >> 8;
  int rem = blk & 255;
  int i0 = (rem >> 5) * 64;
  int t0 = (rem & 31) * 2;

  int tid = threadIdx.x;
  int l = tid & 63;
  int wq = tid >> 6;
  int wr = wq >> 1, wc = wq & 1;
  int lr = l & 15;
  int lk = (l >> 4) * 8;

  f32x4 acc00 = {0.f, 0.f, 0.f, 0.f}, acc01 = acc00, acc10 = acc00, acc11 = acc00;

  int srow = tid >> 2;
  int schunk = (tid & 3) * 8;

  const unsigned short* aSrc =
      Abf + ((size_t)(b * N_ + i0 + srow)) * N_ + schunk;
  int ttS = srow >> 5, fS = srow & 31;
  const unsigned short* xSrc =
      xT + ((size_t)((b * T_ + t0 + ttS) * F_ + fS)) * N_ + schunk;

  for (int j0 = 0; j0 < N_; j0 += 32) {
    *(short8*)&as_[srow][schunk] = *(const short8*)(aSrc + j0);
    *(short8*)&xs_[srow][schunk] = *(const short8*)(xSrc + j0);
    __syncthreads();
    short8 a0 = *(const short8*)&as_[wr * 32 + lr][lk];
    short8 a1 = *(const short8*)&as_[wr * 32 + 16 + lr][lk];
    short8 bb0 = *(const short8*)&xs_[wc * 32 + lr][lk];
    short8 bb1 = *(const short8*)&xs_[wc * 32 + 16 + lr][lk];
    acc00 = __builtin_amdgcn_mfma_f32_16x16x32_bf16(a0, bb0, acc00, 0, 0, 0);
    acc01 = __builtin_amdgcn_mfma_f32_16x16x32_bf16(a0, bb1, acc01, 0, 0, 0);
    acc10 = __builtin_amdgcn_mfma_f32_16x16x32_bf16(a1, bb0, acc10, 0, 0, 0);
    acc11 = __builtin_amdgcn_mfma_f32_16x16x32_bf16(a1, bb1, acc11, 0, 0, 0);
    __syncthreads();
  }

  int ibase = i0 + wr * 32 + (l >> 4) * 4;
  int cbase = wc * 32 + (l & 15);
  f32x4 accs[2][2] = {{acc00, acc01}, {acc10, acc11}};
  #pragma unroll
  for (int si = 0; si < 2; ++si)
    #pragma unroll
    for (int sc = 0; sc < 2; ++sc) {
      int col = cbase + sc * 16;
      int t = t0 + (col >> 5), f = col & 31;
      #pragma unroll
      for (int v = 0; v < 4; ++v) {
        int i = ibase + si * 16 + v;
        h[((size_t)((b * T_ + t) * N_ + i)) * F_ + f] = f2bf(accs[si][sc][v]);
      }
    }
}

// ---------------------------------------------------------------------------
// K2: MFMA TCN+attention. One (b,n) per 256-thread block, 4 waves.
// Activations bf16 in LDS as [t][c] rows (stride 72), +2 zero rows for the
// causal dil-2 shift. Wave q owns M-block q*16 of every GEMM. A-fragments
// are per-lane short8 global loads (weights, L2-hot); B-fragments are
// contiguous short8 LDS reads; D written as packed-bf16 8B per lane using
// C/D layout col=lane&15, row=(lane>>4)*4+reg.
// ---------------------------------------------------------------------------
__global__ __launch_bounds__(256) void tcn_attn_kernel(
    const unsigned short* __restrict__ h, const unsigned short* __restrict__ gw_bf,
    const float* __restrict__ gcn_b, const unsigned short* __restrict__ w1a,
    const unsigned short* __restrict__ w1b, const float* __restrict__ b1c,
    const unsigned short* __restrict__ w2a, const unsigned short* __restrict__ w2b,
    const float* __restrict__ b2c, const unsigned short* __restrict__ W12bf,
    const float* __restrict__ b12, const float* __restrict__ Vw,
    const float* __restrict__ Vb, const float* __restrict__ ln_g,
    const float* __restrict__ ln_b, float* __restrict__ out) {
  __shared__ unsigned short hS[64][40];
  __shared__ unsigned short seqS[66][72];
  __shared__ unsigned short o1S[66][72];
  __shared__ unsigned short tcnS[64][72];
  __shared__ float sp4[4][64];
  __shared__ float awS[64];

  int bn = blockIdx.x;
  int n = bn & (N_ - 1);
  int b = bn >> 9;
  int tid = threadIdx.x;
  int l = tid & 63;
  int q = tid >> 6;
  int lr = l & 15;                 // MFMA tile col (t) / A row
  int lk = (l >> 4) * 8;           // MFMA k-chunk
  int c0 = q * 16 + (l >> 4) * 4;  // D rows base for this wave

  // zero causal pad rows
  if (tid < 72) {
    seqS[0][tid] = 0; seqS[1][tid] = 0;
    o1S[0][tid] = 0;  o1S[1][tid] = 0;
  }
  // stage hS[t][f]
  {
    int t = tid >> 2, f0 = (tid & 3) * 8;
    *(short8*)&hS[t][f0] =
        *(const short8*)(h + ((size_t)((b * T_ + t) * N_ + n)) * F_ + f0);
  }
  __syncthreads();

  // ---- GEMM1: seq[g][t] = gw_bf[g][f] @ hS[f][t] + gcn_b ----
  {
    short8 aG = *(const short8*)(gw_bf + (q * 16 + lr) * 32 + lk);
    float4 bias = *(const float4*)(gcn_b + c0);
    #pragma unroll
    for (int nt = 0; nt < 4; ++nt) {
      f32x4 acc = {0.f, 0.f, 0.f, 0.f};
      short8 bh = *(const short8*)&hS[nt * 16 + lr][lk];
      acc = __builtin_amdgcn_mfma_f32_16x16x32_bf16(aG, bh, acc, 0, 0, 0);
      uint2 pv = pack4(acc[0] + bias.x, acc[1] + bias.y,
                       acc[2] + bias.z, acc[3] + bias.w);
      *(uint2*)&seqS[nt * 16 + lr + 2][c0] = pv;
    }
  }
  __syncthreads();

  // ---- conv1: o1 = relu(w1a@seq[t-2] + w1b@seq[t] + b1c) ----
  {
    short8 aA0 = *(const short8*)(w1a + (q * 16 + lr) * 64 + lk);
    short8 aA1 = *(const short8*)(w1a + (q * 16 + lr) * 64 + 32 + lk);
    short8 aB0 = *(const short8*)(w1b + (q * 16 + lr) * 64 + lk);
    short8 aB1 = *(const short8*)(w1b + (q * 16 + lr) * 64 + 32 + lk);
    float4 bias = *(const float4*)(b1c + c0);
    f32x4 acc[4];
    #pragma unroll
    for (int nt = 0; nt < 4; ++nt) acc[nt] = (f32x4){0.f, 0.f, 0.f, 0.f};
    #pragma unroll
    for (int nt = 0; nt < 4; ++nt) {
      int tr = nt * 16 + lr;
      short8 b00 = *(const short8*)&seqS[tr][lk];           // tap0 k0
      short8 b10 = *(const short8*)&seqS[tr + 2][lk];       // tap1 k0
      acc[nt] = __builtin_amdgcn_mfma_f32_16x16x32_bf16(aA0, b00, acc[nt], 0, 0, 0);
      acc[nt] = __builtin_amdgcn_mfma_f32_16x16x32_bf16(aB0, b10, acc[nt], 0, 0, 0);
    }
    #pragma unroll
    for (int nt = 0; nt < 4; ++nt) {
      int tr = nt * 16 + lr;
      short8 b01 = *(const short8*)&seqS[tr][32 + lk];      // tap0 k1
      short8 b11 = *(const short8*)&seqS[tr + 2][32 + lk];  // tap1 k1
      acc[nt] = __builtin_amdgcn_mfma_f32_16x16x32_bf16(aA1, b01, acc[nt], 0, 0, 0);
      acc[nt] = __builtin_amdgcn_mfma_f32_16x16x32_bf16(aB1, b11, acc[nt], 0, 0, 0);
    }
    #pragma unroll
    for (int nt = 0; nt < 4; ++nt) {
      uint2 pv = pack4(fmaxf(acc[nt][0] + bias.x, 0.f),
                       fmaxf(acc[nt][1] + bias.y, 0.f),
                       fmaxf(acc[nt][2] + bias.z, 0.f),
                       fmaxf(acc[nt][3] + bias.w, 0.f));
      *(uint2*)&o1S[nt * 16 + lr + 2][c0] = pv;
    }
  }
  __syncthreads();

  // ---- conv2 + skip: tcn = relu(relu(w2a@o1[t-2]+w2b@o1[t]+b2c) + seq) ----
  {
    short8 aA0 = *(const short8*)(w2a + (q * 16 + lr) * 64 + lk);
    short8 aA1 = *(const short8*)(w2a + (q * 16 + lr) * 64 + 32 + lk);
    short8 aB0 = *(const short8*)(w2b + (q * 16 + lr) * 64 + lk);
    short8 aB1 = *(const short8*)(w2b + (q * 16 + lr) * 64 + 32 + lk);
    float4 bias = *(const float4*)(b2c + c0);
    f32x4 acc[4];
    #pragma unroll
    for (int nt = 0; nt < 4; ++nt) acc[nt] = (f32x4){0.f, 0.f, 0.f, 0.f};
    #pragma unroll
    for (int nt = 0; nt < 4; ++nt) {
      int tr = nt * 16 + lr;
      short8 b00 = *(const short8*)&o1S[tr][lk];
      short8 b10 = *(const short8*)&o1S[tr + 2][lk];
      acc[nt] = __builtin_amdgcn_mfma_f32_16x16x32_bf16(aA0, b00, acc[nt], 0, 0, 0);
      acc[nt] = __builtin_amdgcn_mfma_f32_16x16x32_bf16(aB0, b10, acc[nt], 0, 0, 0);
    }
    #pragma unroll
    for (int nt = 0; nt < 4; ++nt) {
      int tr = nt * 16 + lr;
      short8 b01 = *(const short8*)&o1S[tr][32 + lk];
      short8 b11 = *(const short8*)&o1S[tr + 2][32 + lk];
      acc[nt] = __builtin_amdgcn_mfma_f32_16x16x32_bf16(aA1, b01, acc[nt], 0, 0, 0);
      acc[nt] = __builtin_amdgcn_mfma_f32_16x16x32_bf16(aB1, b11, acc[nt], 0, 0, 0);
    }
    #pragma unroll
    for (int nt = 0; nt < 4; ++nt) {
      int tr = nt * 16 + lr;
      uint2 sk = *(const uint2*)&seqS[tr + 2][c0];
      float s0 = bf2f((unsigned short)(sk.x & 0xffff));
      float s1 = bf2f((unsigned short)(sk.x >> 16));
      float s2 = bf2f((unsigned short)(sk.y & 0xffff));
      float s3 = bf2f((unsigned short)(sk.y >> 16));
      uint2 pv = pack4(fmaxf(fmaxf(acc[nt][0] + bias.x, 0.f) + s0, 0.f),
                       fmaxf(fmaxf(acc[nt][1] + bias.y, 0.f) + s1, 0.f),
                       fmaxf(fmaxf(acc[nt][2] + bias.z, 0.f) + s2, 0.f),
                       fmaxf(fmaxf(acc[nt][3] + bias.w, 0.f) + s3, 0.f));
      *(uint2*)&tcnS[tr][c0] = pv;
    }
  }
  __syncthreads();

  // ---- GEMM4 + scores: pre[d][t] = W12@tcn; part = sum_d Vw*tanh(pre+b12) ----
  {
    short8 aW0 = *(const short8*)(W12bf + (q * 16 + lr) * 64 + lk);
    short8 aW1 = *(const short8*)(W12bf + (q * 16 + lr) * 64 + 32 + lk);
    float4 vwv = *(const float4*)(Vw + c0);
    float4 b12v = *(const float4*)(b12 + c0);
    #pragma unroll
    for (int nt = 0; nt < 4; ++nt) {
      int tr = nt * 16 + lr;
      f32x4 acc = {0.f, 0.f, 0.f, 0.f};
      short8 bb0 = *(const short8*)&tcnS[tr][lk];
      short8 bb1 = *(const short8*)&tcnS[tr][32 + lk];
      acc = __builtin_amdgcn_mfma_f32_16x16x32_bf16(aW0, bb0, acc, 0, 0, 0);
      acc = __builtin_amdgcn_mfma_f32_16x16x32_bf16(aW1, bb1, acc, 0, 0, 0);
      float p = 0.f;
      float bv[4] = {b12v.x, b12v.y, b12v.z, b12v.w};
      float vv[4] = {vwv.x, vwv.y, vwv.z, vwv.w};
      #pragma unroll
      for (int r = 0; r < 4; ++r) {
        float s = acc[r] + bv[r];
        float e = __expf(2.f * s);               // tanh(s) = 1 - 2/(e^{2s}+1)
        p += vv[r] * (1.f - 2.f / (e + 1.f));
      }
      p += __shfl_xor(p, 16);
      p += __shfl_xor(p, 32);
      if (l < 16) sp4[q][nt * 16 + l] = p;
    }
  }
  __syncthreads();

  // ---- softmax over t (wave 0) ----
  if (tid < 64) {
    float s = sp4[0][l] + sp4[1][l] + sp4[2][l] + sp4[3][l] + Vb[0];
    float m = s;
    #pragma unroll
    for (int msk = 1; msk < 64; msk <<= 1) m = fmaxf(m, __shfl_xor(m, msk));
    float e = __expf(s - m);
    float su = e;
    #pragma unroll
    for (int msk = 1; msk < 64; msk <<= 1) su += __shfl_xor(su, msk);
    awS[l] = e / su;
  }
  __syncthreads();

  // ---- attn[c] partials: wave q covers t in [q*16, q*16+16) ----
  {
    float pa = 0.f;
    #pragma unroll
    for (int k = 0; k < 16; ++k)
      pa += bf2f(tcnS[q * 16 + k][l]) * awS[q * 16 + k];
    sp4[q][l] = pa;
  }
  __syncthreads();

  // ---- LayerNorm over c ----
  if (tid < 64) {
    int c = l;
    float a = sp4[0][c] + sp4[1][c] + sp4[2][c] + sp4[3][c];
    float su = a;
    #pragma unroll
    for (int msk = 1; msk < 64; msk <<= 1) su += __shfl_xor(su, msk);
    float mu = su * (1.f / 64.f);
    float dv = a - mu;
    float vv = dv * dv;
    #pragma unroll
    for (int msk = 1; msk < 64; msk <<= 1) vv += __shfl_xor(vv, msk);
    float rs = rsqrtf(vv * (1.f / 64.f) + 1e-5f);
    out[(size_t)bn * C_ + c] = dv * rs * ln_g[c] + ln_b[c];
  }
}

// ---------------------------------------------------------------------------
extern "C" void kernel_launch(void* const* d_in, const int* in_sizes, int n_in,
                              void* d_out, int out_size, void* d_ws, size_t ws_size,
                              hipStream_t stream) {
  (void)in_sizes; (void)n_in; (void)out_size; (void)ws_size;
  const float* x     = (const float*)d_in[0];
  const float* adj   = (const float*)d_in[1];
  const float* gcn_w = (const float*)d_in[2];
  const float* gcn_b = (const float*)d_in[3];
  const float* v1    = (const float*)d_in[4];
  const float* g1    = (const float*)d_in[5];
  const float* b1c   = (const float*)d_in[6];
  const float* v2    = (const float*)d_in[7];
  const float* g2    = (const float*)d_in[8];
  const float* b2c   = (const float*)d_in[9];
  const float* W1    = (const float*)d_in[10];
  const float* b1    = (const float*)d_in[11];
  const float* W2    = (const float*)d_in[12];
  const float* b2    = (const float*)d_in[13];
  const float* Vw    = (const float*)d_in[14];
  const float* Vb    = (const float*)d_in[15];
  const float* ln_g  = (const float*)d_in[16];
  const float* ln_b  = (const float*)d_in[17];
  float* out = (float*)d_out;

  char* ws = (char*)d_ws;
  unsigned short* h    = (unsigned short*)(ws);              // 16,777,216 B
  unsigned short* Abf  = (unsigned short*)(ws + 16777216);   //  4,194,304 B
  unsigned short* xT   = (unsigned short*)(ws + 20971520);   // 16,777,216 B
  float* dd            = (float*)(ws + 37748736);            //     16,384 B
  unsigned short* gw_bf= (unsigned short*)(ws + 37765120);   //      4,096 B
  unsigned short* w1a  = (unsigned short*)(ws + 37769216);   //      8,192 B
  unsigned short* w1b  = (unsigned short*)(ws + 37777408);   //      8,192 B
  unsigned short* w2a  = (unsigned short*)(ws + 37785600);   //      8,192 B
  unsigned short* w2b  = (unsigned short*)(ws + 37793792);   //      8,192 B
  unsigned short* W12bf= (unsigned short*)(ws + 37801984);   //      8,192 B
  float* b12           = (float*)(ws + 37810176);            //        256 B

  deg_kernel<<<(B_ * N_) / 4, 256, 0, stream>>>(adj, dd);
  abf_kernel<<<(B_ * N_) / 4, 256, 0, stream>>>(adj, dd, Abf);
  xT_kernel<<<B_ * T_, 256, 0, stream>>>(x, xT);
  prep_kernel<<<130, 256, 0, stream>>>(v1, g1, v2, g2, W1, W2, b1, b2, gcn_w,
                                       w1a, w1b, w2a, w2b, W12bf, b12, gw_bf);
  gcn_mfma_kernel<<<B_ * 256, 256, 0, stream>>>(Abf, xT, h);
  tcn_attn_kernel<<<B_ * N_, 256, 0, stream>>>(h, gw_bf, gcn_b, w1a, w1b, b1c,
                                               w2a, w2b, b2c, W12bf, b12, Vw,
                                               Vb, ln_g, ln_b, out);
}

// Round 9
// 170.067 us; speedup vs baseline: 3.9093x; 1.1011x over previous
//
#include <hip/hip_runtime.h>
#include <hip/hip_bf16.h>
#include <math.h>

#define B_ 8
#define T_ 64
#define N_ 512
#define F_ 32
#define G_ 64
#define C_ 64

typedef __attribute__((ext_vector_type(8))) short short8;
typedef __attribute__((ext_vector_type(4))) float f32x4;

__device__ __forceinline__ unsigned short f2bf(float x) {
  unsigned u = __float_as_uint(x);
  u += 0x7fffu + ((u >> 16) & 1u);
  return (unsigned short)(u >> 16);
}
__device__ __forceinline__ float bf2f(unsigned short h) {
  return __uint_as_float(((unsigned)h) << 16);
}
// v_cvt_pk_bf16_f32: low16 = bf16(lo), high16 = bf16(hi), RNE
__device__ __forceinline__ unsigned cvtpk(float lo, float hi) {
  unsigned r;
  asm("v_cvt_pk_bf16_f32 %0, %1, %2" : "=v"(r) : "v"(lo), "v"(hi));
  return r;
}
__device__ __forceinline__ uint2 pack4(float a, float b, float c, float d) {
  uint2 r; r.x = cvtpk(a, b); r.y = cvtpk(c, d); return r;
}
// async global->LDS, 16B per lane; dest must be linear (base + lane*16)
#define GLOAD16(gsrc, ldst)                                              \
  __builtin_amdgcn_global_load_lds(                                      \
      (const __attribute__((address_space(1))) unsigned int*)(gsrc),     \
      (__attribute__((address_space(3))) unsigned int*)(ldst), 16, 0, 0)

// ---------------------------------------------------------------------------
// P0: d[b*N+i] = rsqrt(deg)
// ---------------------------------------------------------------------------
__global__ __launch_bounds__(256) void deg_kernel(const float* __restrict__ adj,
                                                  float* __restrict__ d) {
  int row = blockIdx.x * 4 + (threadIdx.x >> 6);
  int lane = threadIdx.x & 63;
  const float* r = adj + (size_t)row * N_;
  float s = 0.f;
  #pragma unroll
  for (int j = lane; j < N_; j += 64) s += r[j];
  #pragma unroll
  for (int m = 1; m < 64; m <<= 1) s += __shfl_xor(s, m);
  if (lane == 0) {
    float deg = s + 1.0f;
    d[row] = (deg > 0.f) ? rsqrtf(deg) : 0.f;
  }
}

// ---------------------------------------------------------------------------
// P1: fused prep. blk<1024: Abf; 1024..1535: xT; 1536..1665: weight prep.
// ---------------------------------------------------------------------------
__global__ __launch_bounds__(256) void prep_all_kernel(
    const float* __restrict__ adj, const float* __restrict__ d,
    const float* __restrict__ x,
    const float* __restrict__ v1, const float* __restrict__ g1,
    const float* __restrict__ v2, const float* __restrict__ g2,
    const float* __restrict__ W1, const float* __restrict__ W2,
    const float* __restrict__ b1, const float* __restrict__ b2,
    const float* __restrict__ gcn_w,
    unsigned short* __restrict__ Abf, unsigned short* __restrict__ xT,
    unsigned short* __restrict__ w1a, unsigned short* __restrict__ w1b,
    unsigned short* __restrict__ w2a, unsigned short* __restrict__ w2b,
    unsigned short* __restrict__ W12bf, float* __restrict__ b12,
    unsigned short* __restrict__ gw_bf) {
  __shared__ float tile[64][33];
  __shared__ float red[4];
  int blk = blockIdx.x;
  int tid = threadIdx.x;

  if (blk < 1024) {
    // ---- Abf[b][i][j] = bf16((adj+I) * d_i * d_j) ----
    int row = blk * 4 + (tid >> 6);
    int lane = tid & 63;
    int b = row >> 9;
    int i = row & (N_ - 1);
    float di = d[row];
    const float* src = adj + (size_t)row * N_;
    unsigned short* dst = Abf + (size_t)row * N_;
    int j0 = lane * 8;
    float4 v0 = *(const float4*)(src + j0);
    float4 v1v = *(const float4*)(src + j0 + 4);
    float vals[8] = {v0.x, v0.y, v0.z, v0.w, v1v.x, v1v.y, v1v.z, v1v.w};
    unsigned short o[8];
    #pragma unroll
    for (int k = 0; k < 8; ++k) {
      int j = j0 + k;
      float a = vals[k] + ((i == j) ? 1.f : 0.f);
      o[k] = f2bf(a * di * d[b * N_ + j]);
    }
    uint4 pv;
    pv.x = (unsigned)o[0] | ((unsigned)o[1] << 16);
    pv.y = (unsigned)o[2] | ((unsigned)o[3] << 16);
    pv.z = (unsigned)o[4] | ((unsigned)o[5] << 16);
    pv.w = (unsigned)o[6] | ((unsigned)o[7] << 16);
    *(uint4*)(dst + j0) = pv;
  } else if (blk < 1536) {
    // ---- xT[b][t][f][j] = bf16(x[b][t][j][f]) ----
    int bt = blk - 1024;
    const float* src = x + (size_t)bt * N_ * F_;
    unsigned short* dst = xT + (size_t)bt * F_ * N_;
    for (int j0 = 0; j0 < N_; j0 += 64) {
      #pragma unroll
      for (int kk = 0; kk < 2; ++kk) {
        int qq = tid + 256 * kk;
        int jl = qq >> 3, fc = qq & 7;
        float4 v = *(const float4*)(src + (size_t)(j0 + jl) * F_ + fc * 4);
        tile[jl][fc * 4 + 0] = v.x;
        tile[jl][fc * 4 + 1] = v.y;
        tile[jl][fc * 4 + 2] = v.z;
        tile[jl][fc * 4 + 3] = v.w;
      }
      __syncthreads();
      {
        int u = tid & 31, fr = tid >> 5;
        #pragma unroll
        for (int ff = 0; ff < 4; ++ff) {
          int f = fr + ff * 8;
          ((unsigned*)(dst + (size_t)f * N_ + j0))[u] =
              cvtpk(tile[2 * u][f], tile[2 * u + 1][f]);
        }
      }
      __syncthreads();
    }
  } else {
    int pblk = blk - 1536;
    if (pblk < 128) {
      int c = pblk & 63;
      const float* v = (pblk < 64) ? v1 : v2;
      const float* g = (pblk < 64) ? g1 : g2;
      unsigned short* wa = (pblk < 64) ? w1a : w2a;
      unsigned short* wb = (pblk < 64) ? w1b : w2b;
      float s = 0.f;
      if (tid < 128) { float t = v[c * 128 + tid]; s = t * t; }
      #pragma unroll
      for (int m = 1; m < 64; m <<= 1) s += __shfl_xor(s, m);
      if ((tid & 63) == 0) red[tid >> 6] = s;
      __syncthreads();
      float sc = g[c] / sqrtf(red[0] + red[1] + red[2] + red[3]);
      if (tid < 64) {
        int gg = tid;
        wa[c * 64 + gg] = f2bf(v[c * 128 + 2 * gg] * sc);
        wb[c * 64 + gg] = f2bf(v[c * 128 + 2 * gg + 1] * sc);
      }
    } else if (pblk == 128) {
      for (int i = tid; i < 4096; i += 256) W12bf[i] = f2bf(W1[i] + W2[i]);
      if (tid < 64) b12[tid] = b1[tid] + b2[tid];
    } else {
      for (int i = tid; i < 2048; i += 256) {
        int g = i >> 5, f = i & 31;
        gw_bf[g * 32 + f] = f2bf(gcn_w[f * 64 + g]);
      }
    }
  }
}

// ---------------------------------------------------------------------------
// K1: MFMA GCN with global_load_lds staging. Unpadded [64][32] tiles are
// linear (dest = base + tid*16B) AND conflict-free for b128 frag reads
// (16 rows x 4 chunks map bijectively over the 1024B span).
// ---------------------------------------------------------------------------
__global__ __launch_bounds__(256) void gcn_mfma_kernel(
    const unsigned short* __restrict__ Abf, const unsigned short* __restrict__ xT,
    unsigned short* __restrict__ h) {
  __shared__ __align__(16) unsigned short as_[64][32];
  __shared__ __align__(16) unsigned short xs_[64][32];

  int blk = blockIdx.x;
  int b = blk >> 8;
  int rem = blk & 255;
  int i0 = (rem >> 5) * 64;
  int t0 = (rem & 31) * 2;

  int tid = threadIdx.x;
  int l = tid & 63;
  int wq = tid >> 6;
  int wr = wq >> 1, wc = wq & 1;
  int lr = l & 15;
  int lk = (l >> 4) * 8;

  f32x4 acc00 = {0.f, 0.f, 0.f, 0.f}, acc01 = acc00, acc10 = acc00, acc11 = acc00;

  int srow = tid >> 2;
  int schunk = (tid & 3) * 8;

  const unsigned short* aSrc =
      Abf + ((size_t)(b * N_ + i0 + srow)) * N_ + schunk;
  int ttS = srow >> 5, fS = srow & 31;
  const unsigned short* xSrc =
      xT + ((size_t)((b * T_ + t0 + ttS) * F_ + fS)) * N_ + schunk;
  unsigned short* aDst = &as_[0][0] + tid * 8;
  unsigned short* xDst = &xs_[0][0] + tid * 8;

  for (int j0 = 0; j0 < N_; j0 += 32) {
    GLOAD16(aSrc + j0, aDst);
    GLOAD16(xSrc + j0, xDst);
    __syncthreads();
    short8 a0 = *(const short8*)&as_[wr * 32 + lr][lk];
    short8 a1 = *(const short8*)&as_[wr * 32 + 16 + lr][lk];
    short8 bb0 = *(const short8*)&xs_[wc * 32 + lr][lk];
    short8 bb1 = *(const short8*)&xs_[wc * 32 + 16 + lr][lk];
    acc00 = __builtin_amdgcn_mfma_f32_16x16x32_bf16(a0, bb0, acc00, 0, 0, 0);
    acc01 = __builtin_amdgcn_mfma_f32_16x16x32_bf16(a0, bb1, acc01, 0, 0, 0);
    acc10 = __builtin_amdgcn_mfma_f32_16x16x32_bf16(a1, bb0, acc10, 0, 0, 0);
    acc11 = __builtin_amdgcn_mfma_f32_16x16x32_bf16(a1, bb1, acc11, 0, 0, 0);
    __syncthreads();
  }

  int ibase = i0 + wr * 32 + (l >> 4) * 4;
  int cbase = wc * 32 + (l & 15);
  f32x4 accs[2][2] = {{acc00, acc01}, {acc10, acc11}};
  #pragma unroll
  for (int si = 0; si < 2; ++si)
    #pragma unroll
    for (int sc = 0; sc < 2; ++sc) {
      int col = cbase + sc * 16;
      int t = t0 + (col >> 5), f = col & 31;
      #pragma unroll
      for (int v = 0; v < 4; ++v) {
        int i = ibase + si * 16 + v;
        h[((size_t)((b * T_ + t) * N_ + i)) * F_ + f] = f2bf(accs[si][sc][v]);
      }
    }
}

// ---------------------------------------------------------------------------
// K2: MFMA TCN+attention. hS staging aliased into tcnS (dead before tcnS is
// written) -> LDS 29.5KB -> 5 blocks/CU. hS via global_load_lds.
// ---------------------------------------------------------------------------
__global__ __launch_bounds__(256) void tcn_attn_kernel(
    const unsigned short* __restrict__ h, const unsigned short* __restrict__ gw_bf,
    const float* __restrict__ gcn_b, const unsigned short* __restrict__ w1a,
    const unsigned short* __restrict__ w1b, const float* __restrict__ b1c,
    const unsigned short* __restrict__ w2a, const unsigned short* __restrict__ w2b,
    const float* __restrict__ b2c, const unsigned short* __restrict__ W12bf,
    const float* __restrict__ b12, const float* __restrict__ Vw,
    const float* __restrict__ Vb, const float* __restrict__ ln_g,
    const float* __restrict__ ln_b, float* __restrict__ out) {
  __shared__ __align__(16) unsigned short seqS[66][72];
  __shared__ __align__(16) unsigned short o1S[66][72];
  __shared__ __align__(16) unsigned short tcnS[64][72];
  __shared__ float sp4[4][64];
  __shared__ float awS[64];

  int bn = blockIdx.x;
  int n = bn & (N_ - 1);
  int b = bn >> 9;
  int tid = threadIdx.x;
  int l = tid & 63;
  int q = tid >> 6;
  int lr = l & 15;                 // MFMA tile col (t) / A row
  int lk = (l >> 4) * 8;           // MFMA k-chunk
  int c0 = q * 16 + (l >> 4) * 4;  // D rows base for this wave

  unsigned short* hS = &tcnS[0][0];   // linear [64][32], dead before conv2

  // zero causal pad rows
  if (tid < 72) {
    seqS[0][tid] = 0; seqS[1][tid] = 0;
    o1S[0][tid] = 0;  o1S[1][tid] = 0;
  }
  // stage hS[t][f] via async DMA (linear dest = base + tid*16B)
  {
    int t = tid >> 2, f0 = (tid & 3) * 8;
    GLOAD16(h + ((size_t)((b * T_ + t) * N_ + n)) * F_ + f0, hS + tid * 8);
  }
  __syncthreads();

  // ---- GEMM1: seq[g][t] = gw_bf[g][f] @ hS[f][t] + gcn_b ----
  {
    short8 aG = *(const short8*)(gw_bf + (q * 16 + lr) * 32 + lk);
    float4 bias = *(const float4*)(gcn_b + c0);
    #pragma unroll
    for (int nt = 0; nt < 4; ++nt) {
      f32x4 acc = {0.f, 0.f, 0.f, 0.f};
      short8 bh = *(const short8*)&hS[(nt * 16 + lr) * 32 + lk];
      acc = __builtin_amdgcn_mfma_f32_16x16x32_bf16(aG, bh, acc, 0, 0, 0);
      uint2 pv = pack4(acc[0] + bias.x, acc[1] + bias.y,
                       acc[2] + bias.z, acc[3] + bias.w);
      *(uint2*)&seqS[nt * 16 + lr + 2][c0] = pv;
    }
  }
  __syncthreads();

  // ---- conv1: o1 = relu(w1a@seq[t-2] + w1b@seq[t] + b1c) ----
  {
    short8 aA0 = *(const short8*)(w1a + (q * 16 + lr) * 64 + lk);
    short8 aA1 = *(const short8*)(w1a + (q * 16 + lr) * 64 + 32 + lk);
    short8 aB0 = *(const short8*)(w1b + (q * 16 + lr) * 64 + lk);
    short8 aB1 = *(const short8*)(w1b + (q * 16 + lr) * 64 + 32 + lk);
    float4 bias = *(const float4*)(b1c + c0);
    f32x4 acc[4];
    #pragma unroll
    for (int nt = 0; nt < 4; ++nt) acc[nt] = (f32x4){0.f, 0.f, 0.f, 0.f};
    #pragma unroll
    for (int nt = 0; nt < 4; ++nt) {
      int tr = nt * 16 + lr;
      short8 b00 = *(const short8*)&seqS[tr][lk];
      short8 b10 = *(const short8*)&seqS[tr + 2][lk];
      acc[nt] = __builtin_amdgcn_mfma_f32_16x16x32_bf16(aA0, b00, acc[nt], 0, 0, 0);
      acc[nt] = __builtin_amdgcn_mfma_f32_16x16x32_bf16(aB0, b10, acc[nt], 0, 0, 0);
    }
    #pragma unroll
    for (int nt = 0; nt < 4; ++nt) {
      int tr = nt * 16 + lr;
      short8 b01 = *(const short8*)&seqS[tr][32 + lk];
      short8 b11 = *(const short8*)&seqS[tr + 2][32 + lk];
      acc[nt] = __builtin_amdgcn_mfma_f32_16x16x32_bf16(aA1, b01, acc[nt], 0, 0, 0);
      acc[nt] = __builtin_amdgcn_mfma_f32_16x16x32_bf16(aB1, b11, acc[nt], 0, 0, 0);
    }
    #pragma unroll
    for (int nt = 0; nt < 4; ++nt) {
      uint2 pv = pack4(fmaxf(acc[nt][0] + bias.x, 0.f),
                       fmaxf(acc[nt][1] + bias.y, 0.f),
                       fmaxf(acc[nt][2] + bias.z, 0.f),
                       fmaxf(acc[nt][3] + bias.w, 0.f));
      *(uint2*)&o1S[nt * 16 + lr + 2][c0] = pv;
    }
  }
  __syncthreads();

  // ---- conv2 + skip: tcn = relu(relu(w2a@o1[t-2]+w2b@o1[t]+b2c) + seq) ----
  {
    short8 aA0 = *(const short8*)(w2a + (q * 16 + lr) * 64 + lk);
    short8 aA1 = *(const short8*)(w2a + (q * 16 + lr) * 64 + 32 + lk);
    short8 aB0 = *(const short8*)(w2b + (q * 16 + lr) * 64 + lk);
    short8 aB1 = *(const short8*)(w2b + (q * 16 + lr) * 64 + 32 + lk);
    float4 bias = *(const float4*)(b2c + c0);
    f32x4 acc[4];
    #pragma unroll
    for (int nt = 0; nt < 4; ++nt) acc[nt] = (f32x4){0.f, 0.f, 0.f, 0.f};
    #pragma unroll
    for (int nt = 0; nt < 4; ++nt) {
      int tr = nt * 16 + lr;
      short8 b00 = *(const short8*)&o1S[tr][lk];
      short8 b10 = *(const short8*)&o1S[tr + 2][lk];
      acc[nt] = __builtin_amdgcn_mfma_f32_16x16x32_bf16(aA0, b00, acc[nt], 0, 0, 0);
      acc[nt] = __builtin_amdgcn_mfma_f32_16x16x32_bf16(aB0, b10, acc[nt], 0, 0, 0);
    }
    #pragma unroll
    for (int nt = 0; nt < 4; ++nt) {
      int tr = nt * 16 + lr;
      short8 b01 = *(const short8*)&o1S[tr][32 + lk];
      short8 b11 = *(const short8*)&o1S[tr + 2][32 + lk];
      acc[nt] = __builtin_amdgcn_mfma_f32_16x16x32_bf16(aA1, b01, acc[nt], 0, 0, 0);
      acc[nt] = __builtin_amdgcn_mfma_f32_16x16x32_bf16(aB1, b11, acc[nt], 0, 0, 0);
    }
    #pragma unroll
    for (int nt = 0; nt < 4; ++nt) {
      int tr = nt * 16 + lr;
      uint2 sk = *(const uint2*)&seqS[tr + 2][c0];
      float s0 = bf2f((unsigned short)(sk.x & 0xffff));
      float s1 = bf2f((unsigned short)(sk.x >> 16));
      float s2 = bf2f((unsigned short)(sk.y & 0xffff));
      float s3 = bf2f((unsigned short)(sk.y >> 16));
      uint2 pv = pack4(fmaxf(fmaxf(acc[nt][0] + bias.x, 0.f) + s0, 0.f),
                       fmaxf(fmaxf(acc[nt][1] + bias.y, 0.f) + s1, 0.f),
                       fmaxf(fmaxf(acc[nt][2] + bias.z, 0.f) + s2, 0.f),
                       fmaxf(fmaxf(acc[nt][3] + bias.w, 0.f) + s3, 0.f));
      *(uint2*)&tcnS[tr][c0] = pv;
    }
  }
  __syncthreads();

  // ---- GEMM4 + scores ----
  {
    short8 aW0 = *(const short8*)(W12bf + (q * 16 + lr) * 64 + lk);
    short8 aW1 = *(const short8*)(W12bf + (q * 16 + lr) * 64 + 32 + lk);
    float4 vwv = *(const float4*)(Vw + c0);
    float4 b12v = *(const float4*)(b12 + c0);
    #pragma unroll
    for (int nt = 0; nt < 4; ++nt) {
      int tr = nt * 16 + lr;
      f32x4 acc = {0.f, 0.f, 0.f, 0.f};
      short8 bb0 = *(const short8*)&tcnS[tr][lk];
      short8 bb1 = *(const short8*)&tcnS[tr][32 + lk];
      acc = __builtin_amdgcn_mfma_f32_16x16x32_bf16(aW0, bb0, acc, 0, 0, 0);
      acc = __builtin_amdgcn_mfma_f32_16x16x32_bf16(aW1, bb1, acc, 0, 0, 0);
      float p = 0.f;
      float bv[4] = {b12v.x, b12v.y, b12v.z, b12v.w};
      float vv[4] = {vwv.x, vwv.y, vwv.z, vwv.w};
      #pragma unroll
      for (int r = 0; r < 4; ++r) {
        float s = acc[r] + bv[r];
        float e = __expf(2.f * s);               // tanh(s) = 1 - 2/(e^{2s}+1)
        p += vv[r] * (1.f - 2.f / (e + 1.f));
      }
      p += __shfl_xor(p, 16);
      p += __shfl_xor(p, 32);
      if (l < 16) sp4[q][nt * 16 + l] = p;
    }
  }
  __syncthreads();

  // ---- softmax over t (wave 0) ----
  if (tid < 64) {
    float s = sp4[0][l] + sp4[1][l] + sp4[2][l] + sp4[3][l] + Vb[0];
    float m = s;
    #pragma unroll
    for (int msk = 1; msk < 64; msk <<= 1) m = fmaxf(m, __shfl_xor(m, msk));
    float e = __expf(s - m);
    float su = e;
    #pragma unroll
    for (int msk = 1; msk < 64; msk <<= 1) su += __shfl_xor(su, msk);
    awS[l] = e / su;
  }
  __syncthreads();

  // ---- attn[c] partials: wave q covers t in [q*16, q*16+16) ----
  {
    float pa = 0.f;
    #pragma unroll
    for (int k = 0; k < 16; ++k)
      pa += bf2f(tcnS[q * 16 + k][l]) * awS[q * 16 + k];
    sp4[q][l] = pa;
  }
  __syncthreads();

  // ---- LayerNorm over c ----
  if (tid < 64) {
    int c = l;
    float a = sp4[0][c] + sp4[1][c] + sp4[2][c] + sp4[3][c];
    float su = a;
    #pragma unroll
    for (int msk = 1; msk < 64; msk <<= 1) su += __shfl_xor(su, msk);
    float mu = su * (1.f / 64.f);
    float dv = a - mu;
    float vv = dv * dv;
    #pragma unroll
    for (int msk = 1; msk < 64; msk <<= 1) vv += __shfl_xor(vv, msk);
    float rs = rsqrtf(vv * (1.f / 64.f) + 1e-5f);
    out[(size_t)bn * C_ + c] = dv * rs * ln_g[c] + ln_b[c];
  }
}

// ---------------------------------------------------------------------------
extern "C" void kernel_launch(void* const* d_in, const int* in_sizes, int n_in,
                              void* d_out, int out_size, void* d_ws, size_t ws_size,
                              hipStream_t stream) {
  (void)in_sizes; (void)n_in; (void)out_size; (void)ws_size;
  const float* x     = (const float*)d_in[0];
  const float* adj   = (const float*)d_in[1];
  const float* gcn_w = (const float*)d_in[2];
  const float* gcn_b = (const float*)d_in[3];
  const float* v1    = (const float*)d_in[4];
  const float* g1    = (const float*)d_in[5];
  const float* b1c   = (const float*)d_in[6];
  const float* v2    = (const float*)d_in[7];
  const float* g2    = (const float*)d_in[8];
  const float* b2c   = (const float*)d_in[9];
  const float* W1    = (const float*)d_in[10];
  const float* b1    = (const float*)d_in[11];
  const float* W2    = (const float*)d_in[12];
  const float* b2    = (const float*)d_in[13];
  const float* Vw    = (const float*)d_in[14];
  const float* Vb    = (const float*)d_in[15];
  const float* ln_g  = (const float*)d_in[16];
  const float* ln_b  = (const float*)d_in[17];
  float* out = (float*)d_out;

  char* ws = (char*)d_ws;
  unsigned short* h    = (unsigned short*)(ws);              // 16,777,216 B
  unsigned short* Abf  = (unsigned short*)(ws + 16777216);   //  4,194,304 B
  unsigned short* xT   = (unsigned short*)(ws + 20971520);   // 16,777,216 B
  float* dd            = (float*)(ws + 37748736);            //     16,384 B
  unsigned short* gw_bf= (unsigned short*)(ws + 37765120);   //      4,096 B
  unsigned short* w1a  = (unsigned short*)(ws + 37769216);   //      8,192 B
  unsigned short* w1b  = (unsigned short*)(ws + 37777408);   //      8,192 B
  unsigned short* w2a  = (unsigned short*)(ws + 37785600);   //      8,192 B
  unsigned short* w2b  = (unsigned short*)(ws + 37793792);   //      8,192 B
  unsigned short* W12bf= (unsigned short*)(ws + 37801984);   //      8,192 B
  float* b12           = (float*)(ws + 37810176);            //        256 B

  deg_kernel<<<(B_ * N_) / 4, 256, 0, stream>>>(adj, dd);
  prep_all_kernel<<<1666, 256, 0, stream>>>(adj, dd, x, v1, g1, v2, g2,
                                            W1, W2, b1, b2, gcn_w,
                                            Abf, xT, w1a, w1b, w2a, w2b,
                                            W12bf, b12, gw_bf);
  gcn_mfma_kernel<<<B_ * 256, 256, 0, stream>>>(Abf, xT, h);
  tcn_attn_kernel<<<B_ * N_, 256, 0, stream>>>(h, gw_bf, gcn_b, w1a, w1b, b1c,
                                               w2a, w2b, b2c, W12bf, b12, Vw,
                                               Vb, ln_g, ln_b, out);
}